// Round 7
// baseline (361.371 us; speedup 1.0000x reference)
//
#include <hip/hip_runtime.h>
#include <math.h>

#define FDIM 64
#define HDIM 128
#define CLSD 64

#define SCAN_ITEMS 8
#define SCAN_CHUNK 2048     // 256 threads * 8

typedef unsigned short ushort_t;
typedef short bfrag __attribute__((ext_vector_type(8)));   // 8 bf16 (4 VGPRs)
typedef float f32x4 __attribute__((ext_vector_type(4)));

#define LOG2E 1.4426950408889634f

// raw hardware exp2 / rcp (1-ulp class; error irrelevant vs 1.15e-2 threshold)
__device__ __forceinline__ float ex2(float x){ float r; asm("v_exp_f32 %0, %1" : "=v"(r) : "v"(x)); return r; }
__device__ __forceinline__ float rcp_(float x){ float r; asm("v_rcp_f32 %0, %1" : "=v"(r) : "v"(x)); return r; }
__device__ __forceinline__ float fsigmoid(float x){ return rcp_(1.0f + ex2(-LOG2E*x)); }
__device__ __forceinline__ float ftanh(float x){ return 1.0f - 2.0f*rcp_(1.0f + ex2(2.0f*LOG2E*x)); }

__device__ __forceinline__ ushort_t f2bf(float f){
    unsigned int u = __float_as_uint(f);
    unsigned int r = (u + 0x7FFFu + ((u >> 16) & 1u)) >> 16;
    return (ushort_t)r;
}
__device__ __forceinline__ float bf2f(ushort_t b){
    return __uint_as_float(((unsigned int)b) << 16);
}

// ---------------- graph prep ----------------

// xw = x @ W_gcn  ([N,64]@[64,64]); 16 nodes per 256-thread block, W+x in LDS
__global__ void k_xw(const float* __restrict__ x, const float* __restrict__ W,
                     float* __restrict__ xw, int N){
    __shared__ float Wl[64*64];
    __shared__ float xs[16*64];
    int t = threadIdx.x;
    const float4* W4 = (const float4*)W;
    float4* Wl4 = (float4*)Wl;
    #pragma unroll
    for (int i = 0; i < 4; ++i) Wl4[i*256 + t] = W4[i*256 + t];
    int nb = blockIdx.x*16;
    {
        int row = t >> 4, c4 = t & 15;
        int gr = nb + row;
        float4 v = (gr < N) ? ((const float4*)x)[(size_t)gr*16 + c4]
                            : make_float4(0.f,0.f,0.f,0.f);
        ((float4*)xs)[row*16 + c4] = v;
    }
    __syncthreads();
    int c = t & 63, mg = t >> 6;     // wave mg handles rows mg, mg+4, mg+8, mg+12
    float a0=0.f, a1=0.f, a2=0.f, a3=0.f;
    #pragma unroll
    for (int k = 0; k < 64; ++k){
        float wv = Wl[k*64 + c];
        a0 += xs[(mg+ 0)*64 + k]*wv;
        a1 += xs[(mg+ 4)*64 + k]*wv;
        a2 += xs[(mg+ 8)*64 + k]*wv;
        a3 += xs[(mg+12)*64 + k]*wv;
    }
    if (nb+mg      < N) xw[(size_t)(nb+mg     )*64 + c] = a0;
    if (nb+mg+4    < N) xw[(size_t)(nb+mg+4   )*64 + c] = a1;
    if (nb+mg+8    < N) xw[(size_t)(nb+mg+8   )*64 + c] = a2;
    if (nb+mg+12   < N) xw[(size_t)(nb+mg+12  )*64 + c] = a3;
}

__global__ void k_deg(const int* __restrict__ ei, int* __restrict__ cnt, int E){
    int i = blockIdx.x*blockDim.x + threadIdx.x;
    if (i < E) atomicAdd(&cnt[ei[E + i]], 1);
}

__launch_bounds__(256)
__global__ void k_scanA(const int* __restrict__ cnt, int* __restrict__ off,
                        int* __restrict__ bsum, int N){
    __shared__ int s[256];
    int t = threadIdx.x;
    int base = blockIdx.x*SCAN_CHUNK + t*SCAN_ITEMS;
    int v[SCAN_ITEMS];
    int tsum = 0;
    #pragma unroll
    for (int j = 0; j < SCAN_ITEMS; ++j){
        int idx = base + j;
        v[j] = (idx < N) ? cnt[idx] : 0;
        tsum += v[j];
    }
    s[t] = tsum;
    __syncthreads();
    #pragma unroll
    for (int d = 1; d < 256; d <<= 1){
        int u = (t >= d) ? s[t-d] : 0;
        __syncthreads();
        if (t >= d) s[t] += u;
        __syncthreads();
    }
    int run = (t > 0) ? s[t-1] : 0;
    #pragma unroll
    for (int j = 0; j < SCAN_ITEMS; ++j){
        int idx = base + j;
        if (idx < N) off[idx] = run;
        run += v[j];
    }
    if (t == 255) bsum[blockIdx.x] = s[255];
}

__launch_bounds__(256)
__global__ void k_scanB(int* __restrict__ bsum, int* __restrict__ bbase, int nb){
    __shared__ int s[256];
    int t = threadIdx.x;
    s[t] = (t < nb) ? bsum[t] : 0;
    __syncthreads();
    #pragma unroll
    for (int d = 1; d < 256; d <<= 1){
        int u = (t >= d) ? s[t-d] : 0;
        __syncthreads();
        if (t >= d) s[t] += u;
        __syncthreads();
    }
    if (t < nb) bbase[t] = (t > 0) ? s[t-1] : 0;
}

__global__ void k_scanC(const int* __restrict__ cnt, int* __restrict__ off,
                        int* __restrict__ cur, float* __restrict__ dinv,
                        const int* __restrict__ bbase, int N, int E){
    int i = blockIdx.x*blockDim.x + threadIdx.x;
    if (i < N){
        int o = off[i] + bbase[i / SCAN_CHUNK];
        off[i] = o;
        cur[i] = o;
        dinv[i] = rsqrtf((float)cnt[i] + 1.0f);
    }
    if (i == 0) off[N] = E;
}

__global__ void k_fill(const int* __restrict__ ei, int* __restrict__ cur,
                       int* __restrict__ csr, int E){
    int i = blockIdx.x*blockDim.x + threadIdx.x;
    if (i < E){
        int s = ei[i], d = ei[E + i];
        int slot = atomicAdd(&cur[d], 1);
        csr[slot] = s;
    }
}

__launch_bounds__(256)
__global__ void k_gather(const int* __restrict__ off, const int* __restrict__ csr,
                         const float* __restrict__ dinv, const float* __restrict__ xw,
                         const float* __restrict__ bg, float* __restrict__ h, int N){
    int tid = blockIdx.x*256 + threadIdx.x;
    int n = tid >> 4, l = tid & 15;
    if (n >= N) return;
    int beg = off[n], end = off[n+1];
    const float4* xw4 = (const float4*)xw;
    float4 acc = make_float4(0.f,0.f,0.f,0.f);
    int idx = beg;
    for (; idx + 4 <= end; idx += 4){
        int s0 = csr[idx+0], s1 = csr[idx+1], s2 = csr[idx+2], s3 = csr[idx+3];
        float w0 = dinv[s0], w1 = dinv[s1], w2 = dinv[s2], w3 = dinv[s3];
        float4 v0 = xw4[(size_t)s0*16 + l];
        float4 v1 = xw4[(size_t)s1*16 + l];
        float4 v2 = xw4[(size_t)s2*16 + l];
        float4 v3 = xw4[(size_t)s3*16 + l];
        acc.x += w0*v0.x + w1*v1.x + w2*v2.x + w3*v3.x;
        acc.y += w0*v0.y + w1*v1.y + w2*v2.y + w3*v3.y;
        acc.z += w0*v0.z + w1*v1.z + w2*v2.z + w3*v3.z;
        acc.w += w0*v0.w + w1*v1.w + w2*v2.w + w3*v3.w;
    }
    for (; idx < end; ++idx){
        int s = csr[idx];
        float w = dinv[s];
        float4 v = xw4[(size_t)s*16 + l];
        acc.x += w*v.x; acc.y += w*v.y; acc.z += w*v.z; acc.w += w*v.w;
    }
    float dn = dinv[n];
    float4 sv = xw4[(size_t)n*16 + l];
    float4 b4 = ((const float4*)bg)[l];
    acc.x = dn*(acc.x + dn*sv.x) + b4.x;
    acc.y = dn*(acc.y + dn*sv.y) + b4.y;
    acc.z = dn*(acc.z + dn*sv.z) + b4.z;
    acc.w = dn*(acc.w + dn*sv.w) + b4.w;
    ((float4*)h)[(size_t)n*16 + l] = acc;
}

// ---------------- weight prep (+ cnt zeroing fused) ----------------
__global__ void k_prep(const float* __restrict__ Wx, const float* __restrict__ Th,
                       const float* __restrict__ Wl,
                       const float* __restrict__ bga, const float* __restrict__ bco,
                       ushort_t* __restrict__ Bhi, ushort_t* __restrict__ Blo,
                       ushort_t* __restrict__ Lhi, ushort_t* __restrict__ Llo,
                       float* __restrict__ bsum, int* __restrict__ cnt, int N){
    int tid = blockIdx.x*256 + threadIdx.x;
    if (tid < 98304){                       // 192 x 512 gate weights
        int k = tid >> 9, col = tid & 511;
        float v = (k < 64) ? Wx[k*512 + col] : Th[(k-64)*512 + col];
        int g = col >> 7, hc = col & 127;
        int w = hc >> 5, within = hc & 31;
        int c8 = g*2 + (within >> 4);
        int T = w*8 + c8;
        int s = k >> 5;
        int lane = ((k >> 3) & 3)*16 + (within & 15);
        int pos = ((T*6 + s)*64 + lane)*8 + (k & 7);
        ushort_t hb = f2bf(v);
        Bhi[pos] = hb;
        Blo[pos] = f2bf(v - bf2f(hb));
    } else if (tid < 106496){               // 128 x 64 Wlin
        int i = tid - 98304;
        int k = i >> 6, col = i & 63;
        float v = Wl[k*64 + col];
        int ct = col >> 4;
        int s = k >> 5;
        int lane = ((k >> 3) & 3)*16 + (col & 15);
        int pos = ((ct*4 + s)*64 + lane)*8 + (k & 7);
        ushort_t hb = f2bf(v);
        Lhi[pos] = hb;
        Llo[pos] = f2bf(v - bf2f(hb));
    } else if (tid < 107008){
        int c = tid - 106496;
        bsum[c] = bga[c] + bco[c];
    } else if (tid - 107008 < N){
        cnt[tid - 107008] = 0;
    }
}

// ---------------- fused MFMA kernel ----------------
// 64 nodes / block, 512 threads = 8 waves (wm in {0,1} x wn in {0..3}).
// 2-pass split: D = Ah*Bh + Ah*Bl (B weights split hi/lo, A rounded to bf16).
// Also writes the oh1 passthrough (reads h1 anyway during staging).
__launch_bounds__(512)
__global__ void k_fused(const float* __restrict__ h,  const float* __restrict__ h1,
                        const float* __restrict__ h2,
                        const ushort_t* __restrict__ Bhi, const ushort_t* __restrict__ Blo,
                        const ushort_t* __restrict__ Lhi, const ushort_t* __restrict__ Llo,
                        const float* __restrict__ bsum, const float* __restrict__ wc,
                        const float* __restrict__ blin,
                        float* __restrict__ outC, float* __restrict__ oh1,
                        ushort_t* __restrict__ zb, int N)
{
    __shared__ __align__(16) char smem[33792];
    ushort_t* Ah = (ushort_t*)smem;             // phase 1: [4 mt][6 s][64 lanes] x16B = 24576 B

    const int t    = threadIdx.x;
    const int w    = t >> 6;
    const int wm   = w >> 2;                    // 0..1  (M half)
    const int wn   = w & 3;                     // 0..3  (col quarter)
    const int lane = t & 63;
    const int nb   = blockIdx.x * 64;

    // ---- stage A = [h | h1] rows nb..nb+63 as bf16 fragments; oh1 passthrough ----
    #pragma unroll
    for (int ff = 0; ff < 3; ++ff){
        int f   = ff*512 + t;                   // 0..1535 = (mt, s, l)
        int mt  = f / 384;
        int rem = f - mt*384;
        int s   = rem >> 6, l = rem & 63;
        int row = mt*16 + (l & 15);
        int k0  = s*32 + ((l >> 4) & 3)*8;
        int gr  = nb + row;
        float v[8];
        if (gr < N){
            const float* src = (k0 < 64) ? (h  + (size_t)gr*64  + k0)
                                         : (h1 + (size_t)gr*128 + (k0 - 64));
            float4 p0 = ((const float4*)src)[0];
            float4 p1 = ((const float4*)src)[1];
            v[0]=p0.x; v[1]=p0.y; v[2]=p0.z; v[3]=p0.w;
            v[4]=p1.x; v[5]=p1.y; v[6]=p1.z; v[7]=p1.w;
            if (k0 >= 64){                      // h1 passthrough to output
                float4* dst = (float4*)&oh1[(size_t)gr*128 + (k0 - 64)];
                dst[0] = p0; dst[1] = p1;
            }
        } else {
            #pragma unroll
            for (int j = 0; j < 8; ++j) v[j] = 0.0f;
        }
        unsigned int hp[4];
        #pragma unroll
        for (int j = 0; j < 4; ++j){
            hp[j] = (unsigned int)f2bf(v[2*j]) | ((unsigned int)f2bf(v[2*j+1]) << 16);
        }
        ((int4*)Ah)[f] = make_int4((int)hp[0],(int)hp[1],(int)hp[2],(int)hp[3]);
    }
    __syncthreads();

    // ---- gates GEMM: K=192 (6 steps), wave (wm,wn): rows wm*32+0..31, col tiles wn*8+c8 ----
    f32x4 acc[2][8];
    #pragma unroll
    for (int mt = 0; mt < 2; ++mt)
        #pragma unroll
        for (int c8 = 0; c8 < 8; ++c8)
            acc[mt][c8] = (f32x4){0.f,0.f,0.f,0.f};

    const bfrag* AF  = (const bfrag*)Ah;
    const bfrag* BhF = (const bfrag*)Bhi;
    const bfrag* BlF = (const bfrag*)Blo;

    #pragma unroll
    for (int s = 0; s < 6; ++s){
        bfrag a0 = AF[((wm*2+0)*6 + s)*64 + lane];
        bfrag a1 = AF[((wm*2+1)*6 + s)*64 + lane];
        #pragma unroll
        for (int c8 = 0; c8 < 8; ++c8){
            int T = wn*8 + c8;
            bfrag bh = BhF[(T*6 + s)*64 + lane];
            bfrag bl = BlF[(T*6 + s)*64 + lane];
            acc[0][c8] = __builtin_amdgcn_mfma_f32_16x16x32_bf16(a0, bh, acc[0][c8], 0,0,0);
            acc[0][c8] = __builtin_amdgcn_mfma_f32_16x16x32_bf16(a0, bl, acc[0][c8], 0,0,0);
            acc[1][c8] = __builtin_amdgcn_mfma_f32_16x16x32_bf16(a1, bh, acc[1][c8], 0,0,0);
            acc[1][c8] = __builtin_amdgcn_mfma_f32_16x16x32_bf16(a1, bl, acc[1][c8], 0,0,0);
        }
    }
    __syncthreads();    // A region dead

    ushort_t* Hh   = (ushort_t*)smem;           // [4 mh][4 s'][64] x16B = 16384 B
    float*    Ltile = (float*)(smem + 16384);   // [64][68] fp32 = 17408 B

    // ---- LSTM elementwise, in-register ----
    #pragma unroll
    for (int hc_t = 0; hc_t < 2; ++hc_t){
        int hc  = wn*32 + hc_t*16 + (lane & 15);
        float bi = bsum[hc],       bfv = bsum[128 + hc];
        float bc = bsum[256 + hc], bo  = bsum[384 + hc];
        float wci = wc[hc], wcf = wc[128 + hc], wco = wc[256 + hc];
        #pragma unroll
        for (int mt = 0; mt < 2; ++mt){
            #pragma unroll
            for (int rr = 0; rr < 4; ++rr){
                int row = wm*32 + mt*16 + ((lane >> 4) & 3)*4 + rr;
                int gr  = nb + row;
                float gi = acc[mt][0 + hc_t][rr] + bi;
                float gf = acc[mt][2 + hc_t][rr] + bfv;
                float gc = acc[mt][4 + hc_t][rr] + bc;
                float go = acc[mt][6 + hc_t][rr] + bo;
                float hv = (gr < N) ? h2[(size_t)gr*128 + hc] : 0.0f;
                float I  = fsigmoid(gi + wci*hv);
                float Fg = fsigmoid(gf + wcf*hv);
                float C  = Fg*hv + I*ftanh(gc);
                float O  = fsigmoid(go + wco*C);
                float hn = O*ftanh(C);
                if (gr < N) outC[(size_t)gr*128 + hc] = C;
                float hr = fmaxf(hn, 0.0f);
                // scatter relu(Hn) as logits-A fragment: k = hc, k-step = wn
                int l2  = (row & 15) + (hc_t*2 + ((lane >> 3) & 1))*16;
                int pos = (((wm*2 + mt)*4 + wn)*64 + l2)*8 + (lane & 7);
                Hh[pos] = f2bf(hr);
            }
        }
    }
    __syncthreads();

    // ---- logits GEMM: K=128 (4 steps); wave (wm,wn): rows wm*32+.., class tile wn ----
    const bfrag* HF  = (const bfrag*)Hh;
    const bfrag* LhF = (const bfrag*)Lhi;
    const bfrag* LlF = (const bfrag*)Llo;
    f32x4 acc2[2];
    acc2[0] = (f32x4){0.f,0.f,0.f,0.f};
    acc2[1] = (f32x4){0.f,0.f,0.f,0.f};
    #pragma unroll
    for (int sp = 0; sp < 4; ++sp){
        bfrag a0 = HF[((wm*2+0)*4 + sp)*64 + lane];
        bfrag a1 = HF[((wm*2+1)*4 + sp)*64 + lane];
        bfrag bh = LhF[(wn*4 + sp)*64 + lane];
        bfrag bl = LlF[(wn*4 + sp)*64 + lane];
        acc2[0] = __builtin_amdgcn_mfma_f32_16x16x32_bf16(a0, bh, acc2[0], 0,0,0);
        acc2[0] = __builtin_amdgcn_mfma_f32_16x16x32_bf16(a0, bl, acc2[0], 0,0,0);
        acc2[1] = __builtin_amdgcn_mfma_f32_16x16x32_bf16(a1, bh, acc2[1], 0,0,0);
        acc2[1] = __builtin_amdgcn_mfma_f32_16x16x32_bf16(a1, bl, acc2[1], 0,0,0);
    }
    {
        int cls = wn*16 + (lane & 15);
        float bv = blin[cls];
        #pragma unroll
        for (int mtl = 0; mtl < 2; ++mtl){
            #pragma unroll
            for (int rr = 0; rr < 4; ++rr){
                int row = wm*32 + mtl*16 + ((lane >> 4) & 3)*4 + rr;
                Ltile[row*68 + cls] = acc2[mtl][rr] + bv;
            }
        }
    }
    __syncthreads();

    // ---- softmax + bf16 z write: 8 threads per node ----
    {
        int m = t >> 3, q = t & 7;
        const float4* Lr = (const float4*)&Ltile[m*68 + q*8];
        float4 v0 = Lr[0], v1 = Lr[1];
        float mx = fmaxf(fmaxf(fmaxf(v0.x,v0.y),fmaxf(v0.z,v0.w)),
                         fmaxf(fmaxf(v1.x,v1.y),fmaxf(v1.z,v1.w)));
        #pragma unroll
        for (int off = 1; off < 8; off <<= 1) mx = fmaxf(mx, __shfl_xor(mx, off, 64));
        float e[8];
        e[0]=ex2(LOG2E*(v0.x-mx)); e[1]=ex2(LOG2E*(v0.y-mx));
        e[2]=ex2(LOG2E*(v0.z-mx)); e[3]=ex2(LOG2E*(v0.w-mx));
        e[4]=ex2(LOG2E*(v1.x-mx)); e[5]=ex2(LOG2E*(v1.y-mx));
        e[6]=ex2(LOG2E*(v1.z-mx)); e[7]=ex2(LOG2E*(v1.w-mx));
        float s8 = e[0]+e[1]+e[2]+e[3]+e[4]+e[5]+e[6]+e[7];
        #pragma unroll
        for (int off = 1; off < 8; off <<= 1) s8 += __shfl_xor(s8, off, 64);
        float inv = rcp_(s8);
        if (nb + m < N){
            unsigned int u0 = (unsigned int)f2bf(e[0]*inv) | ((unsigned int)f2bf(e[1]*inv) << 16);
            unsigned int u1 = (unsigned int)f2bf(e[2]*inv) | ((unsigned int)f2bf(e[3]*inv) << 16);
            unsigned int u2 = (unsigned int)f2bf(e[4]*inv) | ((unsigned int)f2bf(e[5]*inv) << 16);
            unsigned int u3 = (unsigned int)f2bf(e[6]*inv) | ((unsigned int)f2bf(e[7]*inv) << 16);
            ((int4*)zb)[(size_t)(nb+m)*8 + q] = make_int4((int)u0,(int)u1,(int)u2,(int)u3);
        }
    }
}

// r[e] = dot64(z[src], z[dst]) on bf16 z; 8 lanes x 16B per edge
__launch_bounds__(256)
__global__ void k_dec(const int* __restrict__ eli, const ushort_t* __restrict__ zb,
                      float* __restrict__ r, int EL){
    int tid = blockIdx.x*256 + threadIdx.x;
    int e = tid >> 3, l = tid & 7;
    if (e >= EL) return;
    int s = eli[e], d = eli[EL + e];
    int4 a = ((const int4*)zb)[(size_t)s*8 + l];
    int4 b = ((const int4*)zb)[(size_t)d*8 + l];
    unsigned int ua[4] = {(unsigned)a.x,(unsigned)a.y,(unsigned)a.z,(unsigned)a.w};
    unsigned int ub[4] = {(unsigned)b.x,(unsigned)b.y,(unsigned)b.z,(unsigned)b.w};
    float p = 0.f;
    #pragma unroll
    for (int j = 0; j < 4; ++j){
        float alo = __uint_as_float(ua[j] << 16);
        float ahi = __uint_as_float(ua[j] & 0xffff0000u);
        float blo = __uint_as_float(ub[j] << 16);
        float bhi = __uint_as_float(ub[j] & 0xffff0000u);
        p += alo*blo + ahi*bhi;
    }
    #pragma unroll
    for (int off = 1; off < 8; off <<= 1) p += __shfl_xor(p, off, 64);
    if (l == 0) r[e] = p;
}

extern "C" void kernel_launch(void* const* d_in, const int* in_sizes, int n_in,
                              void* d_out, int out_size, void* d_ws, size_t ws_size,
                              hipStream_t stream)
{
    const float* x   = (const float*)d_in[0];
    const int*   ei  = (const int*)  d_in[1];
    const int*   eli = (const int*)  d_in[2];
    const float* h1  = (const float*)d_in[3];
    const float* h2  = (const float*)d_in[4];
    const float* Wg  = (const float*)d_in[5];
    const float* bg  = (const float*)d_in[6];
    const float* Wx  = (const float*)d_in[7];
    const float* Th  = (const float*)d_in[8];
    const float* bga = (const float*)d_in[9];
    const float* bco = (const float*)d_in[10];
    const float* wc  = (const float*)d_in[11];
    const float* Wl  = (const float*)d_in[12];
    const float* bl  = (const float*)d_in[13];

    const int N  = in_sizes[0] / FDIM;
    const int E  = in_sizes[1] / 2;
    const int EL = in_sizes[2] / 2;
    const int NSB = (N + SCAN_CHUNK - 1) / SCAN_CHUNK;   // scan blocks (25)

    // workspace layout (4-byte units):
    // xw[N*64] | hbuf[N*64] | zb (N*64 ushort = N*32 slots) | dinv[N] | cnt | off | cur | csr | ...
    float* ws   = (float*)d_ws;
    float* xw   = ws;
    float* hbuf = xw + (size_t)N*64;
    ushort_t* zb = (ushort_t*)(hbuf + (size_t)N*64);
    float* dinv = hbuf + (size_t)N*64 + (size_t)N*32;
    int*   cnt  = (int*)(dinv + N);
    int*   off  = cnt + N;
    int*   cur  = off + N + 1;
    int*   csr  = cur + N;
    int*   bsc  = csr + E;          // scan block sums [<=256]
    int*   bbc  = bsc + 256;        // scan block bases [<=256]
    size_t base = (size_t)((bbc + 256) - (int*)ws);
    base = (base + 3) & ~(size_t)3;              // 16B align
    ushort_t* Bhi = (ushort_t*)(ws + base);      // 98304 bf16
    ushort_t* Blo = Bhi + 98304;
    ushort_t* Lhi = Blo + 98304;                 // 8192 bf16
    ushort_t* Llo = Lhi + 8192;
    float*   bsum = (float*)(Llo + 8192);        // 512 f32

    float* out = (float*)d_out;
    float* r   = out;                            // [EL]
    float* oh1 = out + EL;                       // [N*128] passthrough (written by k_fused)
    float* oC  = out + EL + (size_t)N*HDIM;      // [N*128]

    const int prepTotal = 107008 + N;            // prep sections + cnt zeroing
    k_prep  <<<(prepTotal + 255)/256, 256, 0, stream>>>(Wx, Th, Wl, bga, bco,
                                                        Bhi, Blo, Lhi, Llo, bsum, cnt, N);
    k_xw    <<<(N + 15)/16, 256, 0, stream>>>(x, Wg, xw, N);
    k_deg   <<<(E + 255)/256, 256, 0, stream>>>(ei, cnt, E);
    k_scanA <<<NSB, 256, 0, stream>>>(cnt, off, bsc, N);
    k_scanB <<<1, 256, 0, stream>>>(bsc, bbc, NSB);
    k_scanC <<<(N + 255)/256, 256, 0, stream>>>(cnt, off, cur, dinv, bbc, N, E);
    k_fill  <<<(E + 255)/256, 256, 0, stream>>>(ei, cur, csr, E);
    k_gather<<<(N*16 + 255)/256, 256, 0, stream>>>(off, csr, dinv, xw, bg, hbuf, N);
    k_fused <<<(N + 63)/64, 512, 0, stream>>>(hbuf, h1, h2, Bhi, Blo, Lhi, Llo,
                                              bsum, wc, bl, oC, oh1, zb, N);
    k_dec   <<<(EL*8 + 255)/256, 256, 0, stream>>>(eli, zb, r, EL);
}

// Round 8
// 223.571 us; speedup vs baseline: 1.6164x; 1.6164x over previous
//
#include <hip/hip_runtime.h>
#include <math.h>

#define FDIM 64
#define HDIM 128
#define CLSD 64

#define SCAN_ITEMS 8
#define SCAN_CHUNK 2048     // 256 threads * 8

typedef unsigned short ushort_t;
typedef short bfrag __attribute__((ext_vector_type(8)));   // 8 bf16 (4 VGPRs)
typedef float f32x4 __attribute__((ext_vector_type(4)));

#define LOG2E 1.4426950408889634f

// raw hardware exp2 / rcp (1-ulp class; error irrelevant vs 1.15e-2 threshold)
__device__ __forceinline__ float ex2(float x){ float r; asm("v_exp_f32 %0, %1" : "=v"(r) : "v"(x)); return r; }
__device__ __forceinline__ float rcp_(float x){ float r; asm("v_rcp_f32 %0, %1" : "=v"(r) : "v"(x)); return r; }
__device__ __forceinline__ float fsigmoid(float x){ return rcp_(1.0f + ex2(-LOG2E*x)); }
__device__ __forceinline__ float ftanh(float x){ return 1.0f - 2.0f*rcp_(1.0f + ex2(2.0f*LOG2E*x)); }

__device__ __forceinline__ ushort_t f2bf(float f){
    unsigned int u = __float_as_uint(f);
    unsigned int r = (u + 0x7FFFu + ((u >> 16) & 1u)) >> 16;
    return (ushort_t)r;
}
__device__ __forceinline__ float bf2f(ushort_t b){
    return __uint_as_float(((unsigned int)b) << 16);
}

// ---------------- graph prep ----------------

// xw = x @ W_gcn  ([N,64]@[64,64]); 16 nodes per 256-thread block, W+x in LDS.
// __launch_bounds__(256) is REQUIRED: without it the default 1024-thread bound
// caps VGPR at 64 -> accumulator/address spill -> 481MB scratch writes (r7 bug).
__launch_bounds__(256)
__global__ void k_xw(const float* __restrict__ x, const float* __restrict__ W,
                     float* __restrict__ xw, int N){
    __shared__ float Wl[64*64];
    __shared__ float xs[16*64];
    int t = threadIdx.x;
    const float4* W4 = (const float4*)W;
    float4* Wl4 = (float4*)Wl;
    #pragma unroll
    for (int i = 0; i < 4; ++i) Wl4[i*256 + t] = W4[i*256 + t];
    int nb = blockIdx.x*16;
    {
        int row = t >> 4, c4 = t & 15;
        int gr = nb + row;
        float4 v = (gr < N) ? ((const float4*)x)[(size_t)gr*16 + c4]
                            : make_float4(0.f,0.f,0.f,0.f);
        ((float4*)xs)[row*16 + c4] = v;
    }
    __syncthreads();
    int c = t & 63, mg = t >> 6;     // wave mg handles rows mg, mg+4, mg+8, mg+12
    float a0=0.f, a1=0.f, a2=0.f, a3=0.f;
    #pragma unroll
    for (int k = 0; k < 64; ++k){
        float wv = Wl[k*64 + c];
        a0 += xs[(mg+ 0)*64 + k]*wv;
        a1 += xs[(mg+ 4)*64 + k]*wv;
        a2 += xs[(mg+ 8)*64 + k]*wv;
        a3 += xs[(mg+12)*64 + k]*wv;
    }
    if (nb+mg      < N) xw[(size_t)(nb+mg     )*64 + c] = a0;
    if (nb+mg+4    < N) xw[(size_t)(nb+mg+4   )*64 + c] = a1;
    if (nb+mg+8    < N) xw[(size_t)(nb+mg+8   )*64 + c] = a2;
    if (nb+mg+12   < N) xw[(size_t)(nb+mg+12  )*64 + c] = a3;
}

__launch_bounds__(256)
__global__ void k_deg(const int* __restrict__ ei, int* __restrict__ cnt, int E){
    int i = blockIdx.x*blockDim.x + threadIdx.x;
    if (i < E) atomicAdd(&cnt[ei[E + i]], 1);
}

__launch_bounds__(256)
__global__ void k_scanA(const int* __restrict__ cnt, int* __restrict__ off,
                        int* __restrict__ bsum, int N){
    __shared__ int s[256];
    int t = threadIdx.x;
    int base = blockIdx.x*SCAN_CHUNK + t*SCAN_ITEMS;
    int v[SCAN_ITEMS];
    int tsum = 0;
    #pragma unroll
    for (int j = 0; j < SCAN_ITEMS; ++j){
        int idx = base + j;
        v[j] = (idx < N) ? cnt[idx] : 0;
        tsum += v[j];
    }
    s[t] = tsum;
    __syncthreads();
    #pragma unroll
    for (int d = 1; d < 256; d <<= 1){
        int u = (t >= d) ? s[t-d] : 0;
        __syncthreads();
        if (t >= d) s[t] += u;
        __syncthreads();
    }
    int run = (t > 0) ? s[t-1] : 0;
    #pragma unroll
    for (int j = 0; j < SCAN_ITEMS; ++j){
        int idx = base + j;
        if (idx < N) off[idx] = run;
        run += v[j];
    }
    if (t == 255) bsum[blockIdx.x] = s[255];
}

__launch_bounds__(256)
__global__ void k_scanB(int* __restrict__ bsum, int* __restrict__ bbase, int nb){
    __shared__ int s[256];
    int t = threadIdx.x;
    s[t] = (t < nb) ? bsum[t] : 0;
    __syncthreads();
    #pragma unroll
    for (int d = 1; d < 256; d <<= 1){
        int u = (t >= d) ? s[t-d] : 0;
        __syncthreads();
        if (t >= d) s[t] += u;
        __syncthreads();
    }
    if (t < nb) bbase[t] = (t > 0) ? s[t-1] : 0;
}

__launch_bounds__(256)
__global__ void k_scanC(const int* __restrict__ cnt, int* __restrict__ off,
                        int* __restrict__ cur, float* __restrict__ dinv,
                        const int* __restrict__ bbase, int N, int E){
    int i = blockIdx.x*blockDim.x + threadIdx.x;
    if (i < N){
        int o = off[i] + bbase[i / SCAN_CHUNK];
        off[i] = o;
        cur[i] = o;
        dinv[i] = rsqrtf((float)cnt[i] + 1.0f);
    }
    if (i == 0) off[N] = E;
}

__launch_bounds__(256)
__global__ void k_fill(const int* __restrict__ ei, int* __restrict__ cur,
                       int* __restrict__ csr, int E){
    int i = blockIdx.x*blockDim.x + threadIdx.x;
    if (i < E){
        int s = ei[i], d = ei[E + i];
        int slot = atomicAdd(&cur[d], 1);
        csr[slot] = s;
    }
}

__launch_bounds__(256)
__global__ void k_gather(const int* __restrict__ off, const int* __restrict__ csr,
                         const float* __restrict__ dinv, const float* __restrict__ xw,
                         const float* __restrict__ bg, float* __restrict__ h, int N){
    int tid = blockIdx.x*256 + threadIdx.x;
    int n = tid >> 4, l = tid & 15;
    if (n >= N) return;
    int beg = off[n], end = off[n+1];
    const float4* xw4 = (const float4*)xw;
    float4 acc = make_float4(0.f,0.f,0.f,0.f);
    int idx = beg;
    for (; idx + 4 <= end; idx += 4){
        int s0 = csr[idx+0], s1 = csr[idx+1], s2 = csr[idx+2], s3 = csr[idx+3];
        float w0 = dinv[s0], w1 = dinv[s1], w2 = dinv[s2], w3 = dinv[s3];
        float4 v0 = xw4[(size_t)s0*16 + l];
        float4 v1 = xw4[(size_t)s1*16 + l];
        float4 v2 = xw4[(size_t)s2*16 + l];
        float4 v3 = xw4[(size_t)s3*16 + l];
        acc.x += w0*v0.x + w1*v1.x + w2*v2.x + w3*v3.x;
        acc.y += w0*v0.y + w1*v1.y + w2*v2.y + w3*v3.y;
        acc.z += w0*v0.z + w1*v1.z + w2*v2.z + w3*v3.z;
        acc.w += w0*v0.w + w1*v1.w + w2*v2.w + w3*v3.w;
    }
    for (; idx < end; ++idx){
        int s = csr[idx];
        float w = dinv[s];
        float4 v = xw4[(size_t)s*16 + l];
        acc.x += w*v.x; acc.y += w*v.y; acc.z += w*v.z; acc.w += w*v.w;
    }
    float dn = dinv[n];
    float4 sv = xw4[(size_t)n*16 + l];
    float4 b4 = ((const float4*)bg)[l];
    acc.x = dn*(acc.x + dn*sv.x) + b4.x;
    acc.y = dn*(acc.y + dn*sv.y) + b4.y;
    acc.z = dn*(acc.z + dn*sv.z) + b4.z;
    acc.w = dn*(acc.w + dn*sv.w) + b4.w;
    ((float4*)h)[(size_t)n*16 + l] = acc;
}

// ---------------- weight prep (+ cnt zeroing fused) ----------------
__launch_bounds__(256)
__global__ void k_prep(const float* __restrict__ Wx, const float* __restrict__ Th,
                       const float* __restrict__ Wl,
                       const float* __restrict__ bga, const float* __restrict__ bco,
                       ushort_t* __restrict__ Bhi, ushort_t* __restrict__ Blo,
                       ushort_t* __restrict__ Lhi, ushort_t* __restrict__ Llo,
                       float* __restrict__ bsum, int* __restrict__ cnt, int N){
    int tid = blockIdx.x*256 + threadIdx.x;
    if (tid < 98304){                       // 192 x 512 gate weights
        int k = tid >> 9, col = tid & 511;
        float v = (k < 64) ? Wx[k*512 + col] : Th[(k-64)*512 + col];
        int g = col >> 7, hc = col & 127;
        int w = hc >> 5, within = hc & 31;
        int c8 = g*2 + (within >> 4);
        int T = w*8 + c8;
        int s = k >> 5;
        int lane = ((k >> 3) & 3)*16 + (within & 15);
        int pos = ((T*6 + s)*64 + lane)*8 + (k & 7);
        ushort_t hb = f2bf(v);
        Bhi[pos] = hb;
        Blo[pos] = f2bf(v - bf2f(hb));
    } else if (tid < 106496){               // 128 x 64 Wlin
        int i = tid - 98304;
        int k = i >> 6, col = i & 63;
        float v = Wl[k*64 + col];
        int ct = col >> 4;
        int s = k >> 5;
        int lane = ((k >> 3) & 3)*16 + (col & 15);
        int pos = ((ct*4 + s)*64 + lane)*8 + (k & 7);
        ushort_t hb = f2bf(v);
        Lhi[pos] = hb;
        Llo[pos] = f2bf(v - bf2f(hb));
    } else if (tid < 107008){
        int c = tid - 106496;
        bsum[c] = bga[c] + bco[c];
    } else if (tid - 107008 < N){
        cnt[tid - 107008] = 0;
    }
}

// ---------------- fused MFMA kernel ----------------
// 64 nodes / block, 512 threads = 8 waves (wm in {0,1} x wn in {0..3}).
// 2-pass split: D = Ah*Bh + Ah*Bl (B weights split hi/lo, A rounded to bf16).
// Also writes the oh1 passthrough (reads h1 anyway during staging).
__launch_bounds__(512)
__global__ void k_fused(const float* __restrict__ h,  const float* __restrict__ h1,
                        const float* __restrict__ h2,
                        const ushort_t* __restrict__ Bhi, const ushort_t* __restrict__ Blo,
                        const ushort_t* __restrict__ Lhi, const ushort_t* __restrict__ Llo,
                        const float* __restrict__ bsum, const float* __restrict__ wc,
                        const float* __restrict__ blin,
                        float* __restrict__ outC, float* __restrict__ oh1,
                        ushort_t* __restrict__ zb, int N)
{
    __shared__ __align__(16) char smem[33792];
    ushort_t* Ah = (ushort_t*)smem;             // phase 1: [4 mt][6 s][64 lanes] x16B = 24576 B

    const int t    = threadIdx.x;
    const int w    = t >> 6;
    const int wm   = w >> 2;                    // 0..1  (M half)
    const int wn   = w & 3;                     // 0..3  (col quarter)
    const int lane = t & 63;
    const int nb   = blockIdx.x * 64;

    // ---- stage A = [h | h1] rows nb..nb+63 as bf16 fragments; oh1 passthrough ----
    #pragma unroll
    for (int ff = 0; ff < 3; ++ff){
        int f   = ff*512 + t;                   // 0..1535 = (mt, s, l)
        int mt  = f / 384;
        int rem = f - mt*384;
        int s   = rem >> 6, l = rem & 63;
        int row = mt*16 + (l & 15);
        int k0  = s*32 + ((l >> 4) & 3)*8;
        int gr  = nb + row;
        float v[8];
        if (gr < N){
            const float* src = (k0 < 64) ? (h  + (size_t)gr*64  + k0)
                                         : (h1 + (size_t)gr*128 + (k0 - 64));
            float4 p0 = ((const float4*)src)[0];
            float4 p1 = ((const float4*)src)[1];
            v[0]=p0.x; v[1]=p0.y; v[2]=p0.z; v[3]=p0.w;
            v[4]=p1.x; v[5]=p1.y; v[6]=p1.z; v[7]=p1.w;
            if (k0 >= 64){                      // h1 passthrough to output
                float4* dst = (float4*)&oh1[(size_t)gr*128 + (k0 - 64)];
                dst[0] = p0; dst[1] = p1;
            }
        } else {
            #pragma unroll
            for (int j = 0; j < 8; ++j) v[j] = 0.0f;
        }
        unsigned int hp[4];
        #pragma unroll
        for (int j = 0; j < 4; ++j){
            hp[j] = (unsigned int)f2bf(v[2*j]) | ((unsigned int)f2bf(v[2*j+1]) << 16);
        }
        ((int4*)Ah)[f] = make_int4((int)hp[0],(int)hp[1],(int)hp[2],(int)hp[3]);
    }
    __syncthreads();

    // ---- gates GEMM: K=192 (6 steps), wave (wm,wn): rows wm*32+0..31, col tiles wn*8+c8 ----
    f32x4 acc[2][8];
    #pragma unroll
    for (int mt = 0; mt < 2; ++mt)
        #pragma unroll
        for (int c8 = 0; c8 < 8; ++c8)
            acc[mt][c8] = (f32x4){0.f,0.f,0.f,0.f};

    const bfrag* AF  = (const bfrag*)Ah;
    const bfrag* BhF = (const bfrag*)Bhi;
    const bfrag* BlF = (const bfrag*)Blo;

    #pragma unroll
    for (int s = 0; s < 6; ++s){
        bfrag a0 = AF[((wm*2+0)*6 + s)*64 + lane];
        bfrag a1 = AF[((wm*2+1)*6 + s)*64 + lane];
        #pragma unroll
        for (int c8 = 0; c8 < 8; ++c8){
            int T = wn*8 + c8;
            bfrag bh = BhF[(T*6 + s)*64 + lane];
            bfrag bl = BlF[(T*6 + s)*64 + lane];
            acc[0][c8] = __builtin_amdgcn_mfma_f32_16x16x32_bf16(a0, bh, acc[0][c8], 0,0,0);
            acc[0][c8] = __builtin_amdgcn_mfma_f32_16x16x32_bf16(a0, bl, acc[0][c8], 0,0,0);
            acc[1][c8] = __builtin_amdgcn_mfma_f32_16x16x32_bf16(a1, bh, acc[1][c8], 0,0,0);
            acc[1][c8] = __builtin_amdgcn_mfma_f32_16x16x32_bf16(a1, bl, acc[1][c8], 0,0,0);
        }
    }
    __syncthreads();    // A region dead

    ushort_t* Hh   = (ushort_t*)smem;           // [4 mh][4 s'][64] x16B = 16384 B
    float*    Ltile = (float*)(smem + 16384);   // [64][68] fp32 = 17408 B

    // ---- LSTM elementwise, in-register ----
    #pragma unroll
    for (int hc_t = 0; hc_t < 2; ++hc_t){
        int hc  = wn*32 + hc_t*16 + (lane & 15);
        float bi = bsum[hc],       bfv = bsum[128 + hc];
        float bc = bsum[256 + hc], bo  = bsum[384 + hc];
        float wci = wc[hc], wcf = wc[128 + hc], wco = wc[256 + hc];
        #pragma unroll
        for (int mt = 0; mt < 2; ++mt){
            #pragma unroll
            for (int rr = 0; rr < 4; ++rr){
                int row = wm*32 + mt*16 + ((lane >> 4) & 3)*4 + rr;
                int gr  = nb + row;
                float gi = acc[mt][0 + hc_t][rr] + bi;
                float gf = acc[mt][2 + hc_t][rr] + bfv;
                float gc = acc[mt][4 + hc_t][rr] + bc;
                float go = acc[mt][6 + hc_t][rr] + bo;
                float hv = (gr < N) ? h2[(size_t)gr*128 + hc] : 0.0f;
                float I  = fsigmoid(gi + wci*hv);
                float Fg = fsigmoid(gf + wcf*hv);
                float C  = Fg*hv + I*ftanh(gc);
                float O  = fsigmoid(go + wco*C);
                float hn = O*ftanh(C);
                if (gr < N) outC[(size_t)gr*128 + hc] = C;
                float hr = fmaxf(hn, 0.0f);
                // scatter relu(Hn) as logits-A fragment: k = hc, k-step = wn
                int l2  = (row & 15) + (hc_t*2 + ((lane >> 3) & 1))*16;
                int pos = (((wm*2 + mt)*4 + wn)*64 + l2)*8 + (lane & 7);
                Hh[pos] = f2bf(hr);
            }
        }
    }
    __syncthreads();

    // ---- logits GEMM: K=128 (4 steps); wave (wm,wn): rows wm*32+.., class tile wn ----
    const bfrag* HF  = (const bfrag*)Hh;
    const bfrag* LhF = (const bfrag*)Lhi;
    const bfrag* LlF = (const bfrag*)Llo;
    f32x4 acc2[2];
    acc2[0] = (f32x4){0.f,0.f,0.f,0.f};
    acc2[1] = (f32x4){0.f,0.f,0.f,0.f};
    #pragma unroll
    for (int sp = 0; sp < 4; ++sp){
        bfrag a0 = HF[((wm*2+0)*4 + sp)*64 + lane];
        bfrag a1 = HF[((wm*2+1)*4 + sp)*64 + lane];
        bfrag bh = LhF[(wn*4 + sp)*64 + lane];
        bfrag bl = LlF[(wn*4 + sp)*64 + lane];
        acc2[0] = __builtin_amdgcn_mfma_f32_16x16x32_bf16(a0, bh, acc2[0], 0,0,0);
        acc2[0] = __builtin_amdgcn_mfma_f32_16x16x32_bf16(a0, bl, acc2[0], 0,0,0);
        acc2[1] = __builtin_amdgcn_mfma_f32_16x16x32_bf16(a1, bh, acc2[1], 0,0,0);
        acc2[1] = __builtin_amdgcn_mfma_f32_16x16x32_bf16(a1, bl, acc2[1], 0,0,0);
    }
    {
        int cls = wn*16 + (lane & 15);
        float bv = blin[cls];
        #pragma unroll
        for (int mtl = 0; mtl < 2; ++mtl){
            #pragma unroll
            for (int rr = 0; rr < 4; ++rr){
                int row = wm*32 + mtl*16 + ((lane >> 4) & 3)*4 + rr;
                Ltile[row*68 + cls] = acc2[mtl][rr] + bv;
            }
        }
    }
    __syncthreads();

    // ---- softmax + bf16 z write: 8 threads per node ----
    {
        int m = t >> 3, q = t & 7;
        const float4* Lr = (const float4*)&Ltile[m*68 + q*8];
        float4 v0 = Lr[0], v1 = Lr[1];
        float mx = fmaxf(fmaxf(fmaxf(v0.x,v0.y),fmaxf(v0.z,v0.w)),
                         fmaxf(fmaxf(v1.x,v1.y),fmaxf(v1.z,v1.w)));
        #pragma unroll
        for (int off = 1; off < 8; off <<= 1) mx = fmaxf(mx, __shfl_xor(mx, off, 64));
        float e[8];
        e[0]=ex2(LOG2E*(v0.x-mx)); e[1]=ex2(LOG2E*(v0.y-mx));
        e[2]=ex2(LOG2E*(v0.z-mx)); e[3]=ex2(LOG2E*(v0.w-mx));
        e[4]=ex2(LOG2E*(v1.x-mx)); e[5]=ex2(LOG2E*(v1.y-mx));
        e[6]=ex2(LOG2E*(v1.z-mx)); e[7]=ex2(LOG2E*(v1.w-mx));
        float s8 = e[0]+e[1]+e[2]+e[3]+e[4]+e[5]+e[6]+e[7];
        #pragma unroll
        for (int off = 1; off < 8; off <<= 1) s8 += __shfl_xor(s8, off, 64);
        float inv = rcp_(s8);
        if (nb + m < N){
            unsigned int u0 = (unsigned int)f2bf(e[0]*inv) | ((unsigned int)f2bf(e[1]*inv) << 16);
            unsigned int u1 = (unsigned int)f2bf(e[2]*inv) | ((unsigned int)f2bf(e[3]*inv) << 16);
            unsigned int u2 = (unsigned int)f2bf(e[4]*inv) | ((unsigned int)f2bf(e[5]*inv) << 16);
            unsigned int u3 = (unsigned int)f2bf(e[6]*inv) | ((unsigned int)f2bf(e[7]*inv) << 16);
            ((int4*)zb)[(size_t)(nb+m)*8 + q] = make_int4((int)u0,(int)u1,(int)u2,(int)u3);
        }
    }
}

// r[e] = dot64(z[src], z[dst]) on bf16 z; 8 lanes x 16B per edge
__launch_bounds__(256)
__global__ void k_dec(const int* __restrict__ eli, const ushort_t* __restrict__ zb,
                      float* __restrict__ r, int EL){
    int tid = blockIdx.x*256 + threadIdx.x;
    int e = tid >> 3, l = tid & 7;
    if (e >= EL) return;
    int s = eli[e], d = eli[EL + e];
    int4 a = ((const int4*)zb)[(size_t)s*8 + l];
    int4 b = ((const int4*)zb)[(size_t)d*8 + l];
    unsigned int ua[4] = {(unsigned)a.x,(unsigned)a.y,(unsigned)a.z,(unsigned)a.w};
    unsigned int ub[4] = {(unsigned)b.x,(unsigned)b.y,(unsigned)b.z,(unsigned)b.w};
    float p = 0.f;
    #pragma unroll
    for (int j = 0; j < 4; ++j){
        float alo = __uint_as_float(ua[j] << 16);
        float ahi = __uint_as_float(ua[j] & 0xffff0000u);
        float blo = __uint_as_float(ub[j] << 16);
        float bhi = __uint_as_float(ub[j] & 0xffff0000u);
        p += alo*blo + ahi*bhi;
    }
    #pragma unroll
    for (int off = 1; off < 8; off <<= 1) p += __shfl_xor(p, off, 64);
    if (l == 0) r[e] = p;
}

extern "C" void kernel_launch(void* const* d_in, const int* in_sizes, int n_in,
                              void* d_out, int out_size, void* d_ws, size_t ws_size,
                              hipStream_t stream)
{
    const float* x   = (const float*)d_in[0];
    const int*   ei  = (const int*)  d_in[1];
    const int*   eli = (const int*)  d_in[2];
    const float* h1  = (const float*)d_in[3];
    const float* h2  = (const float*)d_in[4];
    const float* Wg  = (const float*)d_in[5];
    const float* bg  = (const float*)d_in[6];
    const float* Wx  = (const float*)d_in[7];
    const float* Th  = (const float*)d_in[8];
    const float* bga = (const float*)d_in[9];
    const float* bco = (const float*)d_in[10];
    const float* wc  = (const float*)d_in[11];
    const float* Wl  = (const float*)d_in[12];
    const float* bl  = (const float*)d_in[13];

    const int N  = in_sizes[0] / FDIM;
    const int E  = in_sizes[1] / 2;
    const int EL = in_sizes[2] / 2;
    const int NSB = (N + SCAN_CHUNK - 1) / SCAN_CHUNK;   // scan blocks (25)

    // workspace layout (4-byte units):
    // xw[N*64] | hbuf[N*64] | zb (N*64 ushort = N*32 slots) | dinv[N] | cnt | off | cur | csr | ...
    float* ws   = (float*)d_ws;
    float* xw   = ws;
    float* hbuf = xw + (size_t)N*64;
    ushort_t* zb = (ushort_t*)(hbuf + (size_t)N*64);
    float* dinv = hbuf + (size_t)N*64 + (size_t)N*32;
    int*   cnt  = (int*)(dinv + N);
    int*   off  = cnt + N;
    int*   cur  = off + N + 1;
    int*   csr  = cur + N;
    int*   bsc  = csr + E;          // scan block sums [<=256]
    int*   bbc  = bsc + 256;        // scan block bases [<=256]
    size_t base = (size_t)((bbc + 256) - (int*)ws);
    base = (base + 3) & ~(size_t)3;              // 16B align
    ushort_t* Bhi = (ushort_t*)(ws + base);      // 98304 bf16
    ushort_t* Blo = Bhi + 98304;
    ushort_t* Lhi = Blo + 98304;                 // 8192 bf16
    ushort_t* Llo = Lhi + 8192;
    float*   bsum = (float*)(Llo + 8192);        // 512 f32

    float* out = (float*)d_out;
    float* r   = out;                            // [EL]
    float* oh1 = out + EL;                       // [N*128] passthrough (written by k_fused)
    float* oC  = out + EL + (size_t)N*HDIM;      // [N*128]

    const int prepTotal = 107008 + N;            // prep sections + cnt zeroing
    k_prep  <<<(prepTotal + 255)/256, 256, 0, stream>>>(Wx, Th, Wl, bga, bco,
                                                        Bhi, Blo, Lhi, Llo, bsum, cnt, N);
    k_xw    <<<(N + 15)/16, 256, 0, stream>>>(x, Wg, xw, N);
    k_deg   <<<(E + 255)/256, 256, 0, stream>>>(ei, cnt, E);
    k_scanA <<<NSB, 256, 0, stream>>>(cnt, off, bsc, N);
    k_scanB <<<1, 256, 0, stream>>>(bsc, bbc, NSB);
    k_scanC <<<(N + 255)/256, 256, 0, stream>>>(cnt, off, cur, dinv, bbc, N, E);
    k_fill  <<<(E + 255)/256, 256, 0, stream>>>(ei, cur, csr, E);
    k_gather<<<(N*16 + 255)/256, 256, 0, stream>>>(off, csr, dinv, xw, bg, hbuf, N);
    k_fused <<<(N + 63)/64, 512, 0, stream>>>(hbuf, h1, h2, Bhi, Blo, Lhi, Llo,
                                              bsum, wc, bl, oC, oh1, zb, N);
    k_dec   <<<(EL*8 + 255)/256, 256, 0, stream>>>(eli, zb, r, EL);
}